// Round 11
// baseline (181.443 us; speedup 1.0000x reference)
//
#include <hip/hip_runtime.h>
#include <math.h>

namespace {

constexpr int D = 32;
constexpr int KOBJ = 1023;          // objects 1..1023 (cluster id 0 = noise)
constexpr float QMIN = 0.01f;
constexpr float PTT = 0.9f;
constexpr float METAETA = 4.0f;
constexpr int NB = 512;             // persistent grid: 2 blocks/CU (cap is 4 -> 2x margin)

typedef __attribute__((ext_vector_type(8))) short short8;
typedef __attribute__((ext_vector_type(4))) float f32x4;

#define GLOAD_LDS16(g, l)                                              \
  __builtin_amdgcn_global_load_lds(                                    \
      (const __attribute__((address_space(1))) void*)(g),              \
      (__attribute__((address_space(3))) void*)(l), 16, 0, 0)

__device__ inline float waveSum(float v) {
#pragma unroll
  for (int o = 32; o > 0; o >>= 1) v += __shfl_down(v, o, 64);
  return v;
}

// f32 -> bf16 round-to-nearest-even, as raw ushort bits
__device__ inline ushort f2bf(float f) {
  unsigned u = __float_as_uint(f);
  return (ushort)((u + 0x7FFFu + ((u >> 16) & 1u)) >> 16);
}

// ws: [0,32) acc[8] | [32,40) bar{cnt,gen} | [64,8248) keys | ... (see launch)
// acc: 0=attSum 1=repSum 2=noiseSum 3=noiseCnt 4=hitOkCnt 5=cowardSum
__global__ void k_init(int* wsbase) {
  for (int k = threadIdx.x; k < 2064; k += 256) wsbase[k] = 0;
}

// Grid barrier for a co-resident grid. Arrival/release via agent-scope atomics;
// spin is RELAXED (no per-poll cache invalidation), one ACQUIRE on exit.
// Memory-model: block stores -> __syncthreads -> t0 release-add -> last block
// acq_rel gen bump -> spinners acquire -> __syncthreads.
__device__ inline void gridBar(unsigned* bar, int nb, int t, unsigned phase) {
  __syncthreads();
  if (t == 0) {
    unsigned old = __hip_atomic_fetch_add(&bar[0], 1u, __ATOMIC_ACQ_REL,
                                          __HIP_MEMORY_SCOPE_AGENT);
    if (old == (unsigned)(nb - 1)) {
      __hip_atomic_store(&bar[0], 0u, __ATOMIC_RELAXED, __HIP_MEMORY_SCOPE_AGENT);
      __hip_atomic_fetch_add(&bar[1], 1u, __ATOMIC_ACQ_REL,
                             __HIP_MEMORY_SCOPE_AGENT);
    } else {
      unsigned g;
      do {
        __builtin_amdgcn_s_sleep(16);
        g = __hip_atomic_load(&bar[1], __ATOMIC_RELAXED, __HIP_MEMORY_SCOPE_AGENT);
      } while (g <= phase);
      (void)__hip_atomic_load(&bar[1], __ATOMIC_ACQUIRE, __HIP_MEMORY_SCOPE_AGENT);
    }
  }
  __syncthreads();
}

__global__ __launch_bounds__(256, 4) void k_all(
    const float* __restrict__ beta, const float* __restrict__ x,
    const float* __restrict__ pt, const float* __restrict__ eta,
    const int* __restrict__ recon, const int* __restrict__ cidw, int N,
    float* acc, unsigned* bar, unsigned long long* keys,
    int* __restrict__ alphaArr, float2* __restrict__ qnk,
    ushort* __restrict__ xkbT, float* __restrict__ qArr,
    float* __restrict__ nxArr, int* __restrict__ attkArr, float* out) {
  __shared__ char lds[16384 + 2048 + 64];  // B panel | qnk tile | reduce slots
  float* redS = (float*)(lds + 18432);
  const int t = threadIdx.x;
  const int b = blockIdx.x;
  const int nb = gridDim.x;
  const int wv = t >> 6;
  const int ln = t & 63;

  // ================= phase 1: per-hit =================
  {
    // dtype detect, wave-uniform: int64 cluster_ids (0..1023) => odd words 0
    int odd = 2 * (t & 127) + 1;
    int ow = (odd < N) ? cidw[odd] : 0;
    int is64 = !__any(ow != 0);
    for (int j = b * 256 + t; j < N; j += nb * 256) {
      int cid = is64 ? cidw[2 * j] : cidw[j];
      float bv = beta[j];
      float bc = fminf(fmaxf(bv, 0.f), 1.f - 1e-4f);
      float th = atanhf(bc);
      float q = th * th + QMIN;
      bool ok = (recon[j] > 0) && (pt[j] > PTT) && (fabsf(eta[j]) < METAETA);
      float nx = 0.f;
      const float4* xr = (const float4*)(x + (size_t)j * D);
#pragma unroll
      for (int i2 = 0; i2 < 8; ++i2) {
        float4 v = xr[i2];
        nx += v.x * v.x + v.y * v.y + v.z * v.z + v.w * v.w;
      }
      int attk = (ok && cid >= 1) ? cid : 0;
      qArr[j] = q;
      nxArr[j] = nx;
      attkArr[j] = attk;
      if (cid <= 0) {  // noise hit (rare)
        atomicAdd(&acc[2], bv);
        atomicAdd(&acc[3], 1.f);
      }
      if (attk >= 1) {
        unsigned long long key =
            (((unsigned long long)__float_as_uint(q)) << 32) |
            (unsigned long long)(0xFFFFFFFFu - (unsigned)j);
        atomicMax(&keys[attk - 1], key);
      }
      unsigned long long bal = __ballot(ok);
      if (ln == 0 && bal) atomicAdd(&acc[4], (float)__popcll(bal));
    }
  }
  gridBar(bar, nb, t, 0);

  // ================= phase 2: per-object gather (8 threads/object) =========
  {
    int g = b * 256 + t;
    int obj = g >> 3, p = g & 7;
    float cw = 0.f;
    if (obj <= KOBJ) {
      if (obj < KOBJ) {
        unsigned long long key = keys[obj];
        int alpha = (key != 0ull)
                        ? (int)(0xFFFFFFFFu - (unsigned)(key & 0xFFFFFFFFull))
                        : 0;
        if (p == 0) {
          alphaArr[obj] = alpha;
          qnk[obj] = make_float2(qArr[alpha], nxArr[alpha]);
          cw = 1.f - beta[alpha];
        }
        float4 v = *(const float4*)(x + (size_t)alpha * D + p * 4);
        ushort* dst = xkbT + (size_t)(p >> 1) * 8192 + (size_t)obj * 8 + (p & 1) * 4;
        dst[0] = f2bf(v.x); dst[1] = f2bf(v.y);
        dst[2] = f2bf(v.z); dst[3] = f2bf(v.w);
      } else {  // pad object 1023: never passes d2<1
        if (p == 0) qnk[obj] = make_float2(0.f, 1e30f);
        ushort* dst = xkbT + (size_t)(p >> 1) * 8192 + (size_t)obj * 8 + (p & 1) * 4;
        dst[0] = 0; dst[1] = 0; dst[2] = 0; dst[3] = 0;
      }
    }
    float s = waveSum(cw);
    if (ln == 0 && s != 0.f) atomicAdd(&acc[5], s);
  }
  gridBar(bar, nb, t, 1);

  // ================= phase 3: rep sweep + att ==============================
  // Block owns object-tile ot = b&3 (256 objects), staged ONCE to LDS;
  // sweeps rowgroups rg = b>>2, b>>2+128, ... (128-row tiles).
  // A = bf16(-2x), C = nx_row + nx_k  =>  MFMA output is d2 directly.
  {
    int ot = b & 3;
    int ob = ot * 256;
    // stage 18 KB via global_load_lds (wave-uniform LDS base per 1KB chunk)
    for (int c = wv; c < 18; c += 4) {
      const char* src;
      if (c < 16)  // B panel: slice c>>2, sub-chunk c&3
        src = (const char*)xkbT + (c >> 2) * 16384 + ob * 16 + (c & 3) * 1024;
      else         // qnk tile (2 KB)
        src = (const char*)qnk + ob * 8 + (c - 16) * 1024;
      GLOAD_LDS16(src + ln * 16, lds + c * 1024);
    }
    __syncthreads();  // vmcnt drain for global_load_lds

    int lr = ln & 15;
    int lk = ln >> 4;
    const float2* qnkS = (const float2*)(lds + 16384);
    float rep = 0.f, attc = 0.f, repSub = 0.f;
    int rowgroups = (N + 127) / 128;

    for (int rg = b >> 2; rg < rowgroups; rg += nb >> 2) {
      int rowbase = rg * 128;
      int wrow = rowbase + wv * 32;
      // A fragments: bf16(-2 * x_row), two 16-row tiles per wave
      short8 am2[2];
#pragma unroll
      for (int rt = 0; rt < 2; ++rt) {
        int row = min(wrow + rt * 16 + lr, N - 1);
        const float* p = x + (size_t)row * D + lk * 8;
        float4 v0 = *(const float4*)p;
        float4 v1 = *(const float4*)(p + 4);
        short8 a;
        a[0] = (short)f2bf(-2.f * v0.x); a[1] = (short)f2bf(-2.f * v0.y);
        a[2] = (short)f2bf(-2.f * v0.z); a[3] = (short)f2bf(-2.f * v0.w);
        a[4] = (short)f2bf(-2.f * v1.x); a[5] = (short)f2bf(-2.f * v1.y);
        a[6] = (short)f2bf(-2.f * v1.z); a[7] = (short)f2bf(-2.f * v1.w);
        am2[rt] = a;
      }
      float nxr[2][4], qrow[2][4];
#pragma unroll
      for (int rt = 0; rt < 2; ++rt)
#pragma unroll
        for (int i = 0; i < 4; ++i) {
          int row = wrow + rt * 16 + lk * 4 + i;
          int rc = min(row, N - 1);
          nxr[rt][i] = (row < N) ? nxArr[rc] : 1e37f;
          qrow[rt][i] = (row < N) ? qArr[rc] : 0.f;
        }

#pragma unroll 4
      for (int tt = 0; tt < 16; ++tt) {
        int o = tt * 16 + lr;
        short8 bb = *(const short8*)(lds + lk * 4096 + o * 16);
        float2 qn = qnkS[o];
        float nk = qn.y;
        f32x4 c0 = {nxr[0][0] + nk, nxr[0][1] + nk, nxr[0][2] + nk, nxr[0][3] + nk};
        f32x4 c1 = {nxr[1][0] + nk, nxr[1][1] + nk, nxr[1][2] + nk, nxr[1][3] + nk};
        f32x4 s0 = __builtin_amdgcn_mfma_f32_16x16x32_bf16(am2[0], bb, c0, 0, 0, 0);
        f32x4 s1 = __builtin_amdgcn_mfma_f32_16x16x32_bf16(am2[1], bb, c1, 0, 0, 0);
        float m = fminf(fminf(fminf(s0[0], s0[1]), fminf(s0[2], s0[3])),
                        fminf(fminf(s1[0], s1[1]), fminf(s1[2], s1[3])));
        if (__any(m < 1.f)) {  // rare: some pair within unit distance
          float qk = qn.x;
#pragma unroll
          for (int i = 0; i < 4; ++i) {
            if (s0[i] < 1.f)
              rep += qrow[0][i] * qk * (1.f - sqrtf(fmaxf(s0[i], 1e-12f)));
            if (s1[i] < 1.f)
              rep += qrow[1][i] * qk * (1.f - sqrtf(fmaxf(s1[i], 1e-12f)));
          }
        }
      }

      // exact f32 attractive term (ot==0; 2 threads/row over this rowgroup)
      if (ot == 0) {
        int j = rowbase + (t >> 1);
        int qt = t & 1;
        if (j < N) {
          int attk = attkArr[j];
          if (attk >= 1) {
            int k0 = attk - 1;
            int alpha = alphaArr[k0];
            float2 qn = qnk[k0];  // exact f32 (q_k, nx_k)
            const float4* xj = (const float4*)(x + (size_t)j * D + qt * 16);
            const float4* xk = (const float4*)(x + (size_t)alpha * D + qt * 16);
            float dot = 0.f;
#pragma unroll
            for (int i = 0; i < 4; ++i) {
              float4 a = xj[i], bv = xk[i];
              dot += a.x * bv.x + a.y * bv.y + a.z * bv.z + a.w * bv.w;
            }
            dot += __shfl_xor(dot, 1, 2);
            if (qt == 0) {
              float d2 = nxArr[j] + qn.y - 2.f * dot;
              float w = qArr[j] * qn.x;
              attc += w * fmaxf(d2, 1e-12f);
              if (d2 < 1.f)  // counted by rep sweep: subtract
                repSub += w * (1.f - sqrtf(fmaxf(d2, 1e-12f)));
            }
          }
        }
      }
    }

    // block reduction: one atomic per block per accumulator
    float sw = waveSum(rep);
    float sa = waveSum(attc);
    float sr = waveSum(repSub);
    if (ln == 0) {
      redS[wv] = sw;
      redS[4 + wv] = sa;
      redS[8 + wv] = sr;
    }
    __syncthreads();
    if (t == 0) {
      float tot = (redS[0] + redS[1]) + (redS[2] + redS[3]);
      float ta = (redS[4] + redS[5]) + (redS[6] + redS[7]);
      float tr = (redS[8] + redS[9]) + (redS[10] + redS[11]);
      if (tot != tr) atomicAdd(&acc[1], tot - tr);
      if (ta != 0.f) atomicAdd(&acc[0], ta);
    }
  }
  gridBar(bar, nb, t, 2);

  // ================= phase 4: final scalar ================================
  if (b == 0 && t == 0) {
    double attSum = acc[0], repSum = acc[1], noiseSum = acc[2];
    double noiseCnt = acc[3], okCnt = acc[4], cowardSum = acc[5];
    double norm_att = 1e-9 + okCnt - (double)KOBJ;
    double norm_rep = 1e-9 + (double)(KOBJ - 1) * (double)N;
    double v_att = attSum / norm_att;
    double v_rep = repSum / norm_rep;
    double l_coward = cowardSum / (double)KOBJ;
    double l_noise = noiseSum / fmax(noiseCnt, 1.0);
    out[0] = (float)(v_att + 1.0 * v_rep + 0.1 * l_noise + 0.1 * l_coward);
  }
}

}  // namespace

extern "C" void kernel_launch(void* const* d_in, const int* in_sizes, int n_in,
                              void* d_out, int out_size, void* d_ws, size_t ws_size,
                              hipStream_t stream) {
  const float* beta = (const float*)d_in[0];
  const float* x = (const float*)d_in[1];
  const float* pt = (const float*)d_in[2];
  const float* eta = (const float*)d_in[3];
  const int* recon = (const int*)d_in[4];
  const int* cidw = (const int*)d_in[5];  // int32 or int64 layout, device-detected
  int N = in_sizes[0];
  float* out = (float*)d_out;

  char* w = (char*)d_ws;
  float* acc = (float*)w;                                   // 8 f32
  unsigned* bar = (unsigned*)(w + 32);                      // {cnt, gen}
  unsigned long long* keys = (unsigned long long*)(w + 64); // 1023*8
  int* alphaArr = (int*)(w + 8256);                         // 1023*4
  float2* qnk = (float2*)(w + 12352);                       // 1024*8
  ushort* xkbT = (ushort*)(w + 20544);                      // [4][1024][8] = 65536 B
  float* qArr = (float*)(w + 86080);                        // N*4
  float* nxArr = (float*)(w + 86080 + (size_t)N * 4);       // N*4
  int* attkArr = (int*)(w + 86080 + (size_t)N * 8);         // N*4

  k_init<<<1, 256, 0, stream>>>((int*)w);
  k_all<<<NB, 256, 0, stream>>>(beta, x, pt, eta, recon, cidw, N,
                                acc, bar, keys, alphaArr, qnk, xkbT,
                                qArr, nxArr, attkArr, out);
}

// Round 12
// 76.152 us; speedup vs baseline: 2.3826x; 2.3826x over previous
//
#include <hip/hip_runtime.h>
#include <math.h>

namespace {

constexpr int D = 32;
constexpr int KOBJ = 1023;          // objects 1..1023 (cluster id 0 = noise)
constexpr float QMIN = 0.01f;
constexpr float PTT = 0.9f;
constexpr float METAETA = 4.0f;

typedef __attribute__((ext_vector_type(8))) short short8;
typedef __attribute__((ext_vector_type(4))) float f32x4;

__device__ inline float waveSum(float v) {
#pragma unroll
  for (int o = 32; o > 0; o >>= 1) v += __shfl_down(v, o, 64);
  return v;
}

// f32 -> bf16 round-to-nearest-even, as raw ushort bits
__device__ inline ushort f2bf(float f) {
  unsigned u = __float_as_uint(f);
  return (ushort)((u + 0x7FFFu + ((u >> 16) & 1u)) >> 16);
}

__device__ inline int keyAlpha(unsigned long long key) {
  return (key != 0ull) ? (int)(0xFFFFFFFFu - (unsigned)(key & 0xFFFFFFFFull)) : 0;
}

// ws layout: [0,32) acc[8] | [32,36) ticket | [64,8248) keys | then qArr/nxArr/attkArr
// acc: 0=attSum 1=repSum 2=noiseSum 3=noiseCnt 4=hitOkCnt 5=cowardSum
__global__ void k_init(int* wsbase) {
  for (int k = threadIdx.x; k < 2064; k += 256) wsbase[k] = 0;
}

__global__ __launch_bounds__(256) void k_hits(
    const float* __restrict__ beta, const float* __restrict__ x,
    const float* __restrict__ pt, const float* __restrict__ eta,
    const int* __restrict__ recon, const int* __restrict__ cidw,
    int N, float* acc, unsigned long long* keys,
    float* __restrict__ qArr, float* __restrict__ nxArr,
    int* __restrict__ attkArr) {
  int t = threadIdx.x;
  int j = blockIdx.x * 256 + t;
  // dtype detect, wave-uniform: int64 cluster_ids (0..1023) => odd words all 0
  int odd = 2 * (t & 127) + 1;
  int ow = (odd < N) ? cidw[odd] : 0;
  int is64 = !__any(ow != 0);
  bool ok = false;
  float nsum = 0.f, ncnt = 0.f;
  if (j < N) {
    int cid = is64 ? cidw[2 * j] : cidw[j];
    float b = beta[j];
    float bc = fminf(fmaxf(b, 0.f), 1.f - 1e-4f);
    float tt = atanhf(bc);
    float q = tt * tt + QMIN;
    ok = (recon[j] > 0) && (pt[j] > PTT) && (fabsf(eta[j]) < METAETA);
    float nx = 0.f;
    const float4* xr = (const float4*)(x + (size_t)j * D);
#pragma unroll
    for (int i2 = 0; i2 < 8; ++i2) {
      float4 v = xr[i2];
      nx += v.x * v.x + v.y * v.y + v.z * v.z + v.w * v.w;
    }
    int attk = (ok && cid >= 1) ? cid : 0;
    qArr[j] = q;
    nxArr[j] = nx;
    attkArr[j] = attk;
    if (cid <= 0) { nsum = b; ncnt = 1.f; }  // noise hit
    if (attk >= 1) {
      unsigned long long key =
          (((unsigned long long)__float_as_uint(q)) << 32) |
          (unsigned long long)(0xFFFFFFFFu - (unsigned)j);
      atomicMax(&keys[attk - 1], key);
    }
  }
  // wave-reduced scalar accumulators (avoid same-address atomic storms)
  float ws2 = waveSum(nsum);
  float ws3 = waveSum(ncnt);
  unsigned long long bal = __ballot(ok);
  if ((t & 63) == 0) {
    if (ws3 != 0.f) { atomicAdd(&acc[2], ws2); atomicAdd(&acc[3], ws3); }
    if (bal) atomicAdd(&acc[4], (float)__popcll(bal));
  }
}

// Fused rep + att + coward + final. Grid (rowgroups, 4).
// Block (rg, ot): rows [rg*128, +128) x objects [ot*256, +256).
// Per-block gather: keys -> alpha -> x[alpha] -> bf16 B-panel in LDS (no
// global xkbT round-trip, no k_clusters node).
// A = bf16(-2x), C = nx_row + nx_k  =>  MFMA output is d2 directly.
// Last-finishing block (t0-only acq_rel ticket) computes the final scalar.
__global__ __launch_bounds__(256) void k_pair_all(
    const float* __restrict__ beta, const float* __restrict__ x, int N,
    const float* __restrict__ qArr, const float* __restrict__ nxArr,
    const int* __restrict__ attkArr, const unsigned long long* __restrict__ keys,
    float* acc, unsigned* ticket, float* out) {
  __shared__ char lds[16384 + 2048 + 64];  // B panel | qnk | reduce slots
  float* redS = (float*)(lds + 18432);
  float2* qnkS = (float2*)(lds + 16384);
  int t = threadIdx.x;
  int wv = t >> 6;
  int ln = t & 63;
  int ot = blockIdx.y;
  int ob = ot * 256;
  int rowbase = blockIdx.x * 128;

  // ---- gather this block's 256-object tile straight into LDS ----
  {
    int o = ob + t;
    float qk = 0.f, nk = 1e30f;
    if (o < KOBJ) {
      int alpha = keyAlpha(keys[o]);
      qk = qArr[alpha];
      nk = nxArr[alpha];
      const float4* s4 = (const float4*)(x + (size_t)alpha * D);
      float4 v[8];
#pragma unroll
      for (int i = 0; i < 8; ++i) v[i] = s4[i];
#pragma unroll
      for (int s = 0; s < 4; ++s) {
        float4 v0 = v[2 * s], v1 = v[2 * s + 1];
        short8 a;
        a[0] = (short)f2bf(v0.x); a[1] = (short)f2bf(v0.y);
        a[2] = (short)f2bf(v0.z); a[3] = (short)f2bf(v0.w);
        a[4] = (short)f2bf(v1.x); a[5] = (short)f2bf(v1.y);
        a[6] = (short)f2bf(v1.z); a[7] = (short)f2bf(v1.w);
        *(short8*)(lds + s * 4096 + t * 16) = a;
      }
    } else {  // pad object 1023: never passes d2<1
      short8 z = {0, 0, 0, 0, 0, 0, 0, 0};
#pragma unroll
      for (int s = 0; s < 4; ++s) *(short8*)(lds + s * 4096 + t * 16) = z;
    }
    qnkS[t] = make_float2(qk, nk);
  }

  // ---- coward term (the 4 blockIdx.x==0 blocks; 1 thread/object) ----
  float cw = 0.f;
  if (blockIdx.x == 0) {
    int o = ob + t;
    if (o < KOBJ) cw = 1.f - beta[keyAlpha(keys[o])];
  }

  int lr = ln & 15;
  int lk = ln >> 4;
  int wrow = rowbase + wv * 32;

  // A fragments: bf16(-2 * x_row), two 16-row tiles per wave
  short8 am2[2];
#pragma unroll
  for (int rt = 0; rt < 2; ++rt) {
    int row = min(wrow + rt * 16 + lr, N - 1);  // clamp; pads disabled via nxr
    const float* p = x + (size_t)row * D + lk * 8;
    float4 v0 = *(const float4*)p;
    float4 v1 = *(const float4*)(p + 4);
    short8 a;
    a[0] = (short)f2bf(-2.f * v0.x); a[1] = (short)f2bf(-2.f * v0.y);
    a[2] = (short)f2bf(-2.f * v0.z); a[3] = (short)f2bf(-2.f * v0.w);
    a[4] = (short)f2bf(-2.f * v1.x); a[5] = (short)f2bf(-2.f * v1.y);
    a[6] = (short)f2bf(-2.f * v1.z); a[7] = (short)f2bf(-2.f * v1.w);
    am2[rt] = a;
  }
  float nxr[2][4], qrow[2][4];
#pragma unroll
  for (int rt = 0; rt < 2; ++rt)
#pragma unroll
    for (int i = 0; i < 4; ++i) {
      int row = wrow + rt * 16 + lk * 4 + i;
      int rc = min(row, N - 1);
      nxr[rt][i] = (row < N) ? nxArr[rc] : 1e37f;
      qrow[rt][i] = (row < N) ? qArr[rc] : 0.f;
    }
  __syncthreads();  // gather ds_writes complete

  float rep = 0.f;
#pragma unroll 4
  for (int tt = 0; tt < 16; ++tt) {
    int o = tt * 16 + lr;
    short8 b = *(const short8*)(lds + lk * 4096 + o * 16);
    float2 qn = qnkS[o];
    float nk = qn.y;
    f32x4 c0 = {nxr[0][0] + nk, nxr[0][1] + nk, nxr[0][2] + nk, nxr[0][3] + nk};
    f32x4 c1 = {nxr[1][0] + nk, nxr[1][1] + nk, nxr[1][2] + nk, nxr[1][3] + nk};
    f32x4 s0 = __builtin_amdgcn_mfma_f32_16x16x32_bf16(am2[0], b, c0, 0, 0, 0);
    f32x4 s1 = __builtin_amdgcn_mfma_f32_16x16x32_bf16(am2[1], b, c1, 0, 0, 0);
    float m = fminf(fminf(fminf(s0[0], s0[1]), fminf(s0[2], s0[3])),
                    fminf(fminf(s1[0], s1[1]), fminf(s1[2], s1[3])));
    if (__any(m < 1.f)) {  // rare: some pair within unit distance
      float qk = qn.x;
#pragma unroll
      for (int i = 0; i < 4; ++i) {
        if (s0[i] < 1.f)
          rep += qrow[0][i] * qk * (1.f - sqrtf(fmaxf(s0[i], 1e-12f)));
        if (s1[i] < 1.f)
          rep += qrow[1][i] * qk * (1.f - sqrtf(fmaxf(s1[i], 1e-12f)));
      }
    }
  }

  // ---- exact f32 attractive term (ot==0 blocks; 2 threads/row, inline decode)
  float attc = 0.f, repSub = 0.f;
  if (ot == 0) {
    int j = rowbase + (t >> 1);
    int qt = t & 1;
    if (j < N) {
      int attk = attkArr[j];
      if (attk >= 1) {
        int alpha = keyAlpha(keys[attk - 1]);
        const float4* xj = (const float4*)(x + (size_t)j * D + qt * 16);
        const float4* xk = (const float4*)(x + (size_t)alpha * D + qt * 16);
        float dot = 0.f;
#pragma unroll
        for (int i = 0; i < 4; ++i) {
          float4 a = xj[i], bb = xk[i];
          dot += a.x * bb.x + a.y * bb.y + a.z * bb.z + a.w * bb.w;
        }
        dot += __shfl_xor(dot, 1, 2);
        if (qt == 0) {
          float d2 = nxArr[j] + nxArr[alpha] - 2.f * dot;
          float w = qArr[j] * qArr[alpha];
          attc = w * fmaxf(d2, 1e-12f);
          if (d2 < 1.f)  // att pair was counted by the rep sweep: subtract
            repSub = w * (1.f - sqrtf(fmaxf(d2, 1e-12f)));
        }
      }
    }
  }

  // ---- block reduction: one atomic set per block ----
  float sw = waveSum(rep);
  float sa = waveSum(attc);
  float sr = waveSum(repSub);
  float sc = waveSum(cw);
  if (ln == 0) {
    redS[wv] = sw; redS[4 + wv] = sa; redS[8 + wv] = sr; redS[12 + wv] = sc;
  }
  __syncthreads();
  if (t == 0) {
    float tot = (redS[0] + redS[1]) + (redS[2] + redS[3]);
    float ta = (redS[4] + redS[5]) + (redS[6] + redS[7]);
    float tr = (redS[8] + redS[9]) + (redS[10] + redS[11]);
    float tc = (redS[12] + redS[13]) + (redS[14] + redS[15]);
    if (tot != tr) atomicAdd(&acc[1], tot - tr);
    if (ta != 0.f) atomicAdd(&acc[0], ta);
    if (tc != 0.f) atomicAdd(&acc[5], tc);

    // ---- last-finisher ticket: winner computes the final scalar ----
    unsigned total = gridDim.x * gridDim.y;
    unsigned old = __hip_atomic_fetch_add(ticket, 1u, __ATOMIC_ACQ_REL,
                                          __HIP_MEMORY_SCOPE_AGENT);
    if (old == total - 1) {
      double attSum = __hip_atomic_load(&acc[0], __ATOMIC_RELAXED, __HIP_MEMORY_SCOPE_AGENT);
      double repSum = __hip_atomic_load(&acc[1], __ATOMIC_RELAXED, __HIP_MEMORY_SCOPE_AGENT);
      double noiseSum = __hip_atomic_load(&acc[2], __ATOMIC_RELAXED, __HIP_MEMORY_SCOPE_AGENT);
      double noiseCnt = __hip_atomic_load(&acc[3], __ATOMIC_RELAXED, __HIP_MEMORY_SCOPE_AGENT);
      double okCnt = __hip_atomic_load(&acc[4], __ATOMIC_RELAXED, __HIP_MEMORY_SCOPE_AGENT);
      double cowardSum = __hip_atomic_load(&acc[5], __ATOMIC_RELAXED, __HIP_MEMORY_SCOPE_AGENT);
      double norm_att = 1e-9 + okCnt - (double)KOBJ;
      double norm_rep = 1e-9 + (double)(KOBJ - 1) * (double)N;
      double v_att = attSum / norm_att;
      double v_rep = repSum / norm_rep;
      double l_coward = cowardSum / (double)KOBJ;
      double l_noise = noiseSum / fmax(noiseCnt, 1.0);
      out[0] = (float)(v_att + 1.0 * v_rep + 0.1 * l_noise + 0.1 * l_coward);
    }
  }
}

}  // namespace

extern "C" void kernel_launch(void* const* d_in, const int* in_sizes, int n_in,
                              void* d_out, int out_size, void* d_ws, size_t ws_size,
                              hipStream_t stream) {
  const float* beta = (const float*)d_in[0];
  const float* x = (const float*)d_in[1];
  const float* pt = (const float*)d_in[2];
  const float* eta = (const float*)d_in[3];
  const int* recon = (const int*)d_in[4];
  const int* cidw = (const int*)d_in[5];  // int32 or int64 layout, device-detected
  int N = in_sizes[0];
  float* out = (float*)d_out;

  char* w = (char*)d_ws;
  float* acc = (float*)w;                                   // 8 f32
  unsigned* ticket = (unsigned*)(w + 32);
  unsigned long long* keys = (unsigned long long*)(w + 64); // 1023*8
  float* qArr = (float*)(w + 86080);                        // N*4
  float* nxArr = (float*)(w + 86080 + (size_t)N * 4);       // N*4
  int* attkArr = (int*)(w + 86080 + (size_t)N * 8);         // N*4

  int nbN = (N + 255) / 256;
  int rowgroups = (N + 127) / 128;

  k_init<<<1, 256, 0, stream>>>((int*)w);
  k_hits<<<nbN, 256, 0, stream>>>(beta, x, pt, eta, recon, cidw, N,
                                  acc, keys, qArr, nxArr, attkArr);
  dim3 gp(rowgroups, 4);
  k_pair_all<<<gp, 256, 0, stream>>>(beta, x, N, qArr, nxArr, attkArr,
                                     keys, acc, ticket, out);
}